// Round 8
// baseline (141.854 us; speedup 1.0000x reference)
//
#include <hip/hip_runtime.h>

#define IN_F 256
#define HID 512
#define OUT_F 2048
#define N_HEADS 8
#define BATCH 4096
#define MT 40  // worst-case sum of per-head ceil(cnt/128)

typedef __bf16 bf16_t;
typedef bf16_t bf16x8 __attribute__((ext_vector_type(8)));
typedef float f32x4 __attribute__((ext_vector_type(4)));

__device__ inline unsigned f2bf(float f) {
  union { float f; unsigned u; } v; v.f = f;
  unsigned u = v.u;
  return (u + 0x7FFFu + ((u >> 16) & 1u)) >> 16;  // RNE
}

__device__ inline uint4 pack8(float4 f0, float4 f1) {
  uint4 o;
  o.x = f2bf(f0.x) | (f2bf(f0.y) << 16);
  o.y = f2bf(f0.z) | (f2bf(f0.w) << 16);
  o.z = f2bf(f1.x) | (f2bf(f1.y) << 16);
  o.w = f2bf(f1.z) | (f2bf(f1.w) << 16);
  return o;
}

// map flat M-tile index -> (head, head compact base, local row0, rows); BM=128
__device__ __forceinline__ bool map_tile(const int* cnt, int my, int& head,
                                         int& hbase, int& row0, int& rows) {
  head = -1;
  int acc_t = 0, bsum = 0;
#pragma unroll
  for (int h = 0; h < N_HEADS; ++h) {
    int c = cnt[h];
    int t = (c + 127) >> 7;
    if (head < 0 && my < acc_t + t) {
      head = h;
      int lt = my - acc_t;
      row0 = lt * 128;
      rows = min(128, c - row0);
      hbase = bsum;
    }
    acc_t += t;
    bsum += c;
  }
  return head >= 0;
}

// ---------------- prep: bucket (blocks 0..15) || W1t (16..271) || W2t (272..2319)
__global__ __launch_bounds__(256) void prep_kernel(const int* __restrict__ idxh,
                                                   int* __restrict__ order_h,
                                                   int* __restrict__ cnt,
                                                   const float* __restrict__ W1,
                                                   unsigned short* __restrict__ W1t,
                                                   const float* __restrict__ W2,
                                                   unsigned short* __restrict__ W2t) {
  __shared__ float tile[64][65];
  int tid = threadIdx.x;
  int b = blockIdx.x;
  if (b < 16) {
    int i = b * 256 + tid;
    int h = idxh[i];
    int pos = atomicAdd(&cnt[h], 1);
    order_h[h * BATCH + pos] = i;
    return;
  }
  const float* W; unsigned short* Wt; int K, N, t;
  if (b < 272) { W = W1; Wt = W1t; K = IN_F; N = HID; t = b - 16; }
  else { W = W2; Wt = W2t; K = HID; N = OUT_F; t = b - 272; }
  int nt = N / 64;
  int per_head = nt * (K / 64);
  int h = t / per_head, rem = t % per_head;
  int n0 = (rem % nt) * 64, k0 = (rem / nt) * 64;
  const float* Wh = W + (size_t)h * K * N;
  unsigned short* Wth = Wt + (size_t)h * K * N;
  int c = tid & 63, r0 = tid >> 6;
  for (int rr = r0; rr < 64; rr += 4)
    tile[rr][c] = Wh[(size_t)(k0 + rr) * N + n0 + c];
  __syncthreads();
  for (int rr = r0; rr < 64; rr += 4)
    Wth[(size_t)(n0 + rr) * K + k0 + c] = (unsigned short)f2bf(tile[c][rr]);
}

// ---------------- GEMM1: 128x128 tile, reg->LDS double-buffered pipeline ----
// A from X (fp32, via order_h, convert on the fly), B = W1t. K = 256 (8 iters)
__global__ __launch_bounds__(256) void gemm1_kernel(const float* __restrict__ X,
                                                    const int* __restrict__ order_h,
                                                    const int* __restrict__ cnt,
                                                    const unsigned short* __restrict__ W1t,
                                                    const float* __restrict__ b1,
                                                    unsigned short* __restrict__ Hb) {
  __shared__ __align__(16) unsigned short As[2][128 * 32];
  __shared__ __align__(16) unsigned short Bs[2][128 * 32];
  int head, hbase, row0, rows;
  if (!map_tile(cnt, blockIdx.y, head, hbase, row0, rows)) return;
  int n0 = blockIdx.x * 128;
  int tid = threadIdx.x;
  int wave = tid >> 6, lane = tid & 63;
  int q = lane >> 4, l16 = lane & 15;
  int w_m = wave >> 1, w_n = wave & 1;
  int ldrow = lane >> 2, ldcol = (lane & 3) * 8;
  int c0 = wave * 2, c1 = c0 + 1;
  int lofs0 = c0 * 512 + lane * 8;  // elements; contiguous 16B/lane
  int lofs1 = c1 * 512 + lane * 8;

  // A source rows (two chunks -> two gathered X rows)
  int xr0 = order_h[head * BATCH + row0 + min(c0 * 16 + ldrow, rows - 1)];
  int xr1 = order_h[head * BATCH + row0 + min(c1 * 16 + ldrow, rows - 1)];
  const float* xp0 = X + (size_t)xr0 * IN_F + ldcol;
  const float* xp1 = X + (size_t)xr1 * IN_F + ldcol;
  const unsigned short* Bh = W1t + (size_t)head * HID * IN_F;
  const unsigned short* bp0 = Bh + (size_t)(n0 + c0 * 16 + ldrow) * IN_F + ldcol;
  const unsigned short* bp1 = Bh + (size_t)(n0 + c1 * 16 + ldrow) * IN_F + ldcol;

  float4 fa0 = *(const float4*)xp0, fa1 = *(const float4*)(xp0 + 4);
  float4 fb0 = *(const float4*)xp1, fb1 = *(const float4*)(xp1 + 4);
  uint4 bv0 = *(const uint4*)bp0, bv1 = *(const uint4*)bp1;
  xp0 += 32; xp1 += 32; bp0 += 32; bp1 += 32;

  f32x4 acc[4][4];
#pragma unroll
  for (int i = 0; i < 4; ++i)
#pragma unroll
    for (int j = 0; j < 4; ++j) acc[i][j] = (f32x4){0.f, 0.f, 0.f, 0.f};

  constexpr int KIT = IN_F / 32;
  for (int k = 0; k < KIT; ++k) {
    int cur = k & 1;
    *(uint4*)(As[cur] + lofs0) = pack8(fa0, fa1);
    *(uint4*)(As[cur] + lofs1) = pack8(fb0, fb1);
    *(uint4*)(Bs[cur] + lofs0) = bv0;
    *(uint4*)(Bs[cur] + lofs1) = bv1;
    float4 nfa0, nfa1, nfb0, nfb1; uint4 nbv0, nbv1;
    if (k < KIT - 1) {
      nfa0 = *(const float4*)xp0; nfa1 = *(const float4*)(xp0 + 4);
      nfb0 = *(const float4*)xp1; nfb1 = *(const float4*)(xp1 + 4);
      nbv0 = *(const uint4*)bp0;  nbv1 = *(const uint4*)bp1;
      xp0 += 32; xp1 += 32; bp0 += 32; bp1 += 32;
    }
    __syncthreads();
    bf16x8 af[4], bfr[4];
#pragma unroll
    for (int i = 0; i < 4; ++i) {
      af[i] = *(const bf16x8*)(As[cur] + (w_m * 64 + i * 16 + l16) * 32 + q * 8);
      bfr[i] = *(const bf16x8*)(Bs[cur] + (w_n * 64 + i * 16 + l16) * 32 + q * 8);
    }
#pragma unroll
    for (int mi = 0; mi < 4; ++mi)
#pragma unroll
      for (int ni = 0; ni < 4; ++ni)
        acc[mi][ni] = __builtin_amdgcn_mfma_f32_16x16x32_bf16(af[mi], bfr[ni], acc[mi][ni], 0, 0, 0);
    if (k < KIT - 1) {
      fa0 = nfa0; fa1 = nfa1; fb0 = nfb0; fb1 = nfb1; bv0 = nbv0; bv1 = nbv1;
    }
  }

  float bval[4];
#pragma unroll
  for (int ni = 0; ni < 4; ++ni)
    bval[ni] = b1[(size_t)head * HID + n0 + w_n * 64 + ni * 16 + l16];
#pragma unroll
  for (int mi = 0; mi < 4; ++mi) {
#pragma unroll
    for (int r = 0; r < 4; ++r) {
      int m = w_m * 64 + mi * 16 + q * 4 + r;
      if (m < rows) {
        int p = hbase + row0 + m;
#pragma unroll
        for (int ni = 0; ni < 4; ++ni) {
          int n = n0 + w_n * 64 + ni * 16 + l16;
          float v = acc[mi][ni][r] + bval[ni];
          v = v > 0.f ? v : 0.f;
          Hb[(size_t)p * HID + n] = (unsigned short)f2bf(v);
        }
      }
    }
  }
}

// ---------------- GEMM2: 128x128 tile, reg->LDS double-buffered pipeline ----
// A = Hb (bf16 compact), B = W2t, fp32 scatter to out. K = 512 (16 iters)
__global__ __launch_bounds__(256) void gemm2_kernel(const unsigned short* __restrict__ Hb,
                                                    const unsigned short* __restrict__ W2t,
                                                    const float* __restrict__ b2,
                                                    const int* __restrict__ cnt,
                                                    const int* __restrict__ order_h,
                                                    float* __restrict__ out) {
  __shared__ __align__(16) unsigned short As[2][128 * 32];
  __shared__ __align__(16) unsigned short Bs[2][128 * 32];
  int head, hbase, row0, rows;
  if (!map_tile(cnt, blockIdx.y, head, hbase, row0, rows)) return;
  int n0 = blockIdx.x * 128;
  int tid = threadIdx.x;
  int wave = tid >> 6, lane = tid & 63;
  int q = lane >> 4, l16 = lane & 15;
  int w_m = wave >> 1, w_n = wave & 1;
  int ldrow = lane >> 2, ldcol = (lane & 3) * 8;
  int c0 = wave * 2, c1 = c0 + 1;
  int lofs0 = c0 * 512 + lane * 8;
  int lofs1 = c1 * 512 + lane * 8;

  int ar0 = hbase + row0 + min(c0 * 16 + ldrow, rows - 1);
  int ar1 = hbase + row0 + min(c1 * 16 + ldrow, rows - 1);
  const unsigned short* ap0 = Hb + (size_t)ar0 * HID + ldcol;
  const unsigned short* ap1 = Hb + (size_t)ar1 * HID + ldcol;
  const unsigned short* Bh = W2t + (size_t)head * (size_t)OUT_F * HID;
  const unsigned short* bp0 = Bh + (size_t)(n0 + c0 * 16 + ldrow) * HID + ldcol;
  const unsigned short* bp1 = Bh + (size_t)(n0 + c1 * 16 + ldrow) * HID + ldcol;

  uint4 av0 = *(const uint4*)ap0, av1 = *(const uint4*)ap1;
  uint4 bv0 = *(const uint4*)bp0, bv1 = *(const uint4*)bp1;
  ap0 += 32; ap1 += 32; bp0 += 32; bp1 += 32;

  f32x4 acc[4][4];
#pragma unroll
  for (int i = 0; i < 4; ++i)
#pragma unroll
    for (int j = 0; j < 4; ++j) acc[i][j] = (f32x4){0.f, 0.f, 0.f, 0.f};

  constexpr int KIT = HID / 32;
  for (int k = 0; k < KIT; ++k) {
    int cur = k & 1;
    *(uint4*)(As[cur] + lofs0) = av0;
    *(uint4*)(As[cur] + lofs1) = av1;
    *(uint4*)(Bs[cur] + lofs0) = bv0;
    *(uint4*)(Bs[cur] + lofs1) = bv1;
    uint4 nav0, nav1, nbv0, nbv1;
    if (k < KIT - 1) {
      nav0 = *(const uint4*)ap0; nav1 = *(const uint4*)ap1;
      nbv0 = *(const uint4*)bp0; nbv1 = *(const uint4*)bp1;
      ap0 += 32; ap1 += 32; bp0 += 32; bp1 += 32;
    }
    __syncthreads();
    bf16x8 af[4], bfr[4];
#pragma unroll
    for (int i = 0; i < 4; ++i) {
      af[i] = *(const bf16x8*)(As[cur] + (w_m * 64 + i * 16 + l16) * 32 + q * 8);
      bfr[i] = *(const bf16x8*)(Bs[cur] + (w_n * 64 + i * 16 + l16) * 32 + q * 8);
    }
#pragma unroll
    for (int mi = 0; mi < 4; ++mi)
#pragma unroll
      for (int ni = 0; ni < 4; ++ni)
        acc[mi][ni] = __builtin_amdgcn_mfma_f32_16x16x32_bf16(af[mi], bfr[ni], acc[mi][ni], 0, 0, 0);
    if (k < KIT - 1) { av0 = nav0; av1 = nav1; bv0 = nbv0; bv1 = nbv1; }
  }

  float bval[4];
#pragma unroll
  for (int ni = 0; ni < 4; ++ni)
    bval[ni] = b2[(size_t)head * OUT_F + n0 + w_n * 64 + ni * 16 + l16];
#pragma unroll
  for (int mi = 0; mi < 4; ++mi) {
#pragma unroll
    for (int r = 0; r < 4; ++r) {
      int m = w_m * 64 + mi * 16 + q * 4 + r;
      if (m < rows) {
        int rg = order_h[head * BATCH + row0 + m];
#pragma unroll
        for (int ni = 0; ni < 4; ++ni) {
          int n = n0 + w_n * 64 + ni * 16 + l16;
          out[(size_t)rg * OUT_F + n] = acc[mi][ni][r] + bval[ni];
        }
      }
    }
  }
}

extern "C" void kernel_launch(void* const* d_in, const int* in_sizes, int n_in,
                              void* d_out, int out_size, void* d_ws, size_t ws_size,
                              hipStream_t stream) {
  const float* X = (const float*)d_in[0];
  const int* idxh = (const int*)d_in[1];
  const float* W1 = (const float*)d_in[2];
  const float* b1 = (const float*)d_in[3];
  const float* W2 = (const float*)d_in[4];
  const float* b2 = (const float*)d_in[5];
  float* out = (float*)d_out;

  char* ws = (char*)d_ws;
  int* order_h = (int*)ws;                   ws += (size_t)N_HEADS * BATCH * 4;
  int* cnt = (int*)ws;                       ws += 64;
  unsigned short* W1t = (unsigned short*)ws; ws += (size_t)N_HEADS * IN_F * HID * 2;
  unsigned short* W2t = (unsigned short*)ws; ws += (size_t)N_HEADS * HID * OUT_F * 2;
  unsigned short* Hb = (unsigned short*)ws;  ws += (size_t)BATCH * HID * 2;

  (void)hipMemsetAsync(cnt, 0, 64, stream);
  // d1: bucket (16 blocks) || W1 transpose (256) || W2 transpose (2048)
  prep_kernel<<<dim3(16 + 256 + 2048), dim3(256), 0, stream>>>(idxh, order_h, cnt,
                                                               W1, W1t, W2, W2t);
  // d2: gemm1
  gemm1_kernel<<<dim3(HID / 128, MT), dim3(256), 0, stream>>>(X, order_h, cnt, W1t, b1, Hb);
  // d3: gemm2
  gemm2_kernel<<<dim3(OUT_F / 128, MT), dim3(256), 0, stream>>>(Hb, W2t, b2, cnt, order_h, out);
}